// Round 3
// baseline (2172.480 us; speedup 1.0000x reference)
//
#include <hip/hip_runtime.h>

// LSTM autoencoder: 4 layers 64->64, B=512, T=256 — MFMA-batched recurrence.
// 64 blocks x 512 threads; block owns 8 batch elements.
// Per step: G[256 gates, 8 batch] = Wih.x_t + Whh.h + b via mfma_f32_16x16x32_f16
//   (8 waves x 2 M-tiles; A-frags of W persist in VGPRs as f16).
// Epilogue redistributed via LDS: thread (w=batch, lane=hid) owns ONE unit ->
//   transcendentals spread over all 512 threads. h round-trips through LDS
//   (f16, padded stride) back into B-operand fragments for the next step.
// x fragments prefetched 2 steps ahead from global (recurrence-independent).

typedef _Float16 f16x8 __attribute__((ext_vector_type(8)));
typedef float    f32x4 __attribute__((ext_vector_type(4)));

#define T_SEQ   256
#define HID     64
#define NB      8      // batch elements per block
#define GSTRIDE 260    // dwords; G_lds[n][row] col-major, 16B-aligned rows, bank-spread
#define HSTRIDE 136    // bytes; H_lds[batch][hid] f16, 8B-aligned, ~2-way banks

__device__ __forceinline__ float fast_rcp(float x) { return __builtin_amdgcn_rcpf(x); }
__device__ __forceinline__ float sigm(float x) { return fast_rcp(1.0f + __expf(-x)); }
__device__ __forceinline__ float tanh_fast(float x) {
    return 2.0f * fast_rcp(1.0f + __expf(-2.0f * x)) - 1.0f;
}

__device__ __forceinline__ f16x8 mkfrag(float4 a, float4 b) {
    f16x8 f;
    f[0] = (_Float16)a.x; f[1] = (_Float16)a.y; f[2] = (_Float16)a.z; f[3] = (_Float16)a.w;
    f[4] = (_Float16)b.x; f[5] = (_Float16)b.y; f[6] = (_Float16)b.z; f[7] = (_Float16)b.w;
    return f;
}

__global__ __launch_bounds__(512)
void lstm_layer_mfma(const float* __restrict__ x,    // [B, T, 64]
                     float* __restrict__ out,        // [B, T, 64]
                     const float* __restrict__ Wih,  // [256, 64]
                     const float* __restrict__ Whh,  // [256, 64]
                     const float* __restrict__ bih,  // [256]
                     const float* __restrict__ bhh)  // [256]
{
    __shared__ float    G[NB * GSTRIDE];            // 8320 B, G[n][gate_row]
    __shared__ _Float16 Hs[NB * (HSTRIDE / 2)];     // 1088 B, H[n][hid]

    const int tid  = threadIdx.x;
    const int w    = tid >> 6;        // wave id 0..7 (= epilogue batch idx)
    const int lane = tid & 63;
    const int q    = lane >> 4;       // quad
    const int n    = lane & 15;       // MFMA col index (batch); valid if n < 8
    const int b0   = blockIdx.x * NB;
    const bool xv  = (n < NB);

    // ---- persistent A-fragments: W rows for tiles {w, w+8}, both K halves ----
    // A layout: A[m = lane&15][k = q*8 + j]
    f16x8 Aih[2][2], Ahh[2][2];
    f32x4 biasf[2];
#pragma unroll
    for (int ti = 0; ti < 2; ++ti) {
        const int tile = w + ti * 8;
        const int row  = tile * 16 + n;
#pragma unroll
        for (int kf = 0; kf < 2; ++kf) {
            const float* pi = Wih + row * HID + kf * 32 + q * 8;
            const float* ph = Whh + row * HID + kf * 32 + q * 8;
            f16x8 fi, fh;
#pragma unroll
            for (int j = 0; j < 8; ++j) { fi[j] = (_Float16)pi[j]; fh[j] = (_Float16)ph[j]; }
            Aih[ti][kf] = fi;
            Ahh[ti][kf] = fh;
        }
        // bias in C layout: row = tile*16 + q*4 + r
        f32x4 bf;
#pragma unroll
        for (int r = 0; r < 4; ++r) {
            const int br = tile * 16 + q * 4 + r;
            bf[r] = bih[br] + bhh[br];
        }
        biasf[ti] = bf;
    }

    // ---- zero hidden-state LDS (h0 = 0) ----
    if (tid < NB * (HSTRIDE / 2) / 2) ((int*)Hs)[tid] = 0;

    // ---- x prefetch pipeline (2 steps deep), lanes n<8 only ----
    const float* xbase = x + ((size_t)(b0 + (n & 7)) * T_SEQ) * HID + q * 8;
    float4 xb[2][4];
    auto ldx = [&](int slot, int t) {
        if (xv) {
            const float* p = xbase + t * HID;
            xb[slot][0] = *(const float4*)(p);
            xb[slot][1] = *(const float4*)(p + 4);
            xb[slot][2] = *(const float4*)(p + 32);
            xb[slot][3] = *(const float4*)(p + 36);
        }
    };
    ldx(0, 0);
    ldx(1, 1);

    float c_state = 0.0f;
    float* orow = out + ((size_t)(b0 + w) * T_SEQ) * HID + lane;
    const char* hrow = (const char*)Hs + (n & 7) * HSTRIDE;   // B-frag source
    _Float16* hwr = (_Float16*)((char*)Hs + w * HSTRIDE) + lane;  // epilogue write

    const f32x4 zero4 = {0.f, 0.f, 0.f, 0.f};

    __syncthreads();

    for (int t = 0; t < T_SEQ; ++t) {
        // ---------- phase 1: MFMA ----------
        // B-frags of h: B[k = q*8+j][n] from H_lds[n][hid], 2 K-halves
        f16x8 hf0, hf1, xf0, xf1;
        if (xv) {
            int2 lo0 = *(const int2*)(hrow + q * 16);
            int2 hi0 = *(const int2*)(hrow + q * 16 + 8);
            int2 lo1 = *(const int2*)(hrow + 64 + q * 16);
            int2 hi1 = *(const int2*)(hrow + 64 + q * 16 + 8);
            int4 v0 = make_int4(lo0.x, lo0.y, hi0.x, hi0.y);
            int4 v1 = make_int4(lo1.x, lo1.y, hi1.x, hi1.y);
            hf0 = __builtin_bit_cast(f16x8, v0);
            hf1 = __builtin_bit_cast(f16x8, v1);
            xf0 = mkfrag(xb[t & 1][0], xb[t & 1][1]);
            xf1 = mkfrag(xb[t & 1][2], xb[t & 1][3]);
        } else {
            int4 z = make_int4(0, 0, 0, 0);
            hf0 = hf1 = xf0 = xf1 = __builtin_bit_cast(f16x8, z);
        }
        // prefetch x for t+2 into the slot just consumed
        const int tn = (t + 2 < T_SEQ) ? t + 2 : t;
        ldx(t & 1, tn);

#pragma unroll
        for (int ti = 0; ti < 2; ++ti) {
            f32x4 aX = __builtin_amdgcn_mfma_f32_16x16x32_f16(Aih[ti][0], xf0, biasf[ti], 0, 0, 0);
            aX       = __builtin_amdgcn_mfma_f32_16x16x32_f16(Aih[ti][1], xf1, aX,        0, 0, 0);
            f32x4 aH = __builtin_amdgcn_mfma_f32_16x16x32_f16(Ahh[ti][0], hf0, zero4,     0, 0, 0);
            aH       = __builtin_amdgcn_mfma_f32_16x16x32_f16(Ahh[ti][1], hf1, aH,        0, 0, 0);
            f32x4 gv = aX + aH;
            if (xv) {
                // C layout: col=n, row = tile*16 + q*4 + reg  -> G[n][row], 16B aligned
                float4 st; st.x = gv[0]; st.y = gv[1]; st.z = gv[2]; st.w = gv[3];
                *(float4*)&G[n * GSTRIDE + (w + ti * 8) * 16 + q * 4] = st;
            }
        }
        __syncthreads();

        // ---------- phase 2: epilogue (1 unit per thread: batch=w, hid=lane) ----------
        const float* gcol = &G[w * GSTRIDE];
        float pi = gcol[lane];
        float pf = gcol[64 + lane];
        float pg = gcol[128 + lane];
        float po = gcol[192 + lane];

        float gi = sigm(pi);
        float gf = sigm(pf);
        float gg = tanh_fast(pg);
        float go = sigm(po);
        c_state = gf * c_state + gi * gg;
        float h = go * tanh_fast(c_state);

        orow[t * HID] = h;            // coalesced 256B per wave
        *hwr = (_Float16)h;           // H_lds[w][lane] for next step's B-frags
        __syncthreads();
    }
}

// Fallback scratch in case ws_size is too small (33.6 MB needed)
__device__ float g_scratch[512 * 256 * 64];

extern "C" void kernel_launch(void* const* d_in, const int* in_sizes, int n_in,
                              void* d_out, int out_size, void* d_ws, size_t ws_size,
                              hipStream_t stream) {
    const float* x = (const float*)d_in[0];
    float* out = (float*)d_out;

    const size_t buf_elems = (size_t)512 * 256 * 64;
    float* buf;
    if (ws_size >= buf_elems * sizeof(float)) {
        buf = (float*)d_ws;
    } else {
        void* p = nullptr;
        hipGetSymbolAddress(&p, HIP_SYMBOL(g_scratch));
        buf = (float*)p;
    }

    auto launch = [&](const float* xi, float* ho, int wb) {
        lstm_layer_mfma<<<64, 512, 0, stream>>>(
            xi, ho,
            (const float*)d_in[wb + 0],   // Wih
            (const float*)d_in[wb + 1],   // Whh
            (const float*)d_in[wb + 2],   // bih
            (const float*)d_in[wb + 3]);  // bhh
    };

    launch(x,   buf, 1);    // enc0
    launch(buf, out, 5);    // enc1
    launch(out, buf, 9);    // dec0
    launch(buf, out, 13);   // dec1 (final)
}

// Round 4
// 591.147 us; speedup vs baseline: 3.6750x; 3.6750x over previous
//
#include <hip/hip_runtime.h>

// LSTM autoencoder: 4 layers 64->64, B=512, T=256.
// Producer/consumer wave pair per batch element (block=128):
//   wave0 (producer): xg[t,g] = W_ih . x_t + b  (no recurrence dep, one CHUNK
//     ahead, double-buffered in LDS, x prefetched from global at chunk start)
//   wave1 (consumer): recurrence  g = xg + W_hh . h ; activations; c,h update.
// Round-4 deltas vs round-2 (which ran 1284 cyc/step vs ~450 issue floor):
//   - consumer preloads ALL 8 xg rows into registers after the barrier, full
//     unroll (kills the per-step 120-cyc ds_read stall)
//   - readlane broadcasts hoisted in 16-groups before each dot2 burst
//     (amortizes VALU->SGPR->VALU hazard wait states)
//   - __launch_bounds__(128,1): no spill risk for the extra prefetch regs.

typedef _Float16 h2_t __attribute__((ext_vector_type(2)));

#define T_SEQ  256
#define HID    64
#define CHUNK  8
#define NCHUNK (T_SEQ / CHUNK)   // 32

__device__ __forceinline__ float fast_rcp(float x) { return __builtin_amdgcn_rcpf(x); }
__device__ __forceinline__ float sigm(float x) { return fast_rcp(1.0f + __expf(-x)); }
__device__ __forceinline__ float tanh_fast(float x) {
    return 2.0f * fast_rcp(1.0f + __expf(-2.0f * x)) - 1.0f;
}
__device__ __forceinline__ float dot2acc(h2_t a, h2_t b, float c) {
    return __builtin_amdgcn_fdot2(a, b, c, false);
}
// broadcast lane k's packed f16 pair to all lanes (SGPR operand into dot2)
__device__ __forceinline__ h2_t bc(int v, int k) {
    return __builtin_bit_cast(h2_t, __builtin_amdgcn_readlane(v, k));
}

__global__ __launch_bounds__(128, 1)
void lstm_layer_pc(const float* __restrict__ x,    // [B, T, 64]
                   float* __restrict__ out,        // [B, T, 64]
                   const float* __restrict__ Wih,  // [256, 64]
                   const float* __restrict__ Whh,  // [256, 64]
                   const float* __restrict__ bih,  // [256]
                   const float* __restrict__ bhh)  // [256]
{
    __shared__ float4 xg[2][CHUNK][HID];   // 16 KB double-buffered xg chunks

    const int  tid  = threadIdx.x;
    const int  lane = tid & 63;
    const bool isC  = (tid >= 64);         // wave1 = consumer
    const int  b    = blockIdx.x;

    // ---- role weight matrix (rows g*64+lane), packed f16x2 in VGPRs ----
    h2_t w[4][32];
    {
        const float* Wm = isC ? Whh : Wih;
#pragma unroll
        for (int g = 0; g < 4; ++g) {
            const float2* wr = (const float2*)(Wm + (g * 64 + lane) * HID);
#pragma unroll
            for (int k = 0; k < 32; ++k) {
                float2 v = wr[k];
                h2_t p; p.x = (_Float16)v.x; p.y = (_Float16)v.y;
                w[g][k] = p;
            }
        }
    }

    // ---- producer-only state: biases + x prefetch registers ----
    float bs0 = 0.f, bs1 = 0.f, bs2 = 0.f, bs3 = 0.f;
    const float2* xp = (const float2*)(x + (size_t)b * T_SEQ * HID) + (lane & 31);
    float2 nx[CHUNK];
    if (!isC) {
        bs0 = bih[lane]       + bhh[lane];
        bs1 = bih[64 + lane]  + bhh[64 + lane];
        bs2 = bih[128 + lane] + bhh[128 + lane];
        bs3 = bih[192 + lane] + bhh[192 + lane];
#pragma unroll
        for (int s = 0; s < CHUNK; ++s) nx[s] = xp[s * 32];   // chunk 0
    }

    // ---- consumer-only state ----
    float c_state = 0.0f;
    int   h2r     = 0;                       // packed (h[2k],h[2k+1]) in lane k
    const int a0i = (lane & 31) << 3;        // bpermute byte addr of lane 2*(lane&31)
    float* ob = out + (size_t)b * T_SEQ * HID + lane;

    // iteration c: producer fills chunk c+1, consumer drains chunk c
    for (int c = -1; c < NCHUNK; ++c) {
        if (!isC) {
            const int k = c + 1;
            if (k < NCHUNK) {
                float2 cx[CHUNK];
#pragma unroll
                for (int s = 0; s < CHUNK; ++s) cx[s] = nx[s];
                if (k + 1 < NCHUNK) {        // issue next chunk's loads EARLY
#pragma unroll
                    for (int s = 0; s < CHUNK; ++s)
                        nx[s] = xp[((k + 1) * CHUNK + s) * 32];
                }
#pragma unroll
                for (int s = 0; s < CHUNK; ++s) {
                    h2_t xv; xv.x = (_Float16)cx[s].x; xv.y = (_Float16)cx[s].y;
                    int x2r = __builtin_bit_cast(int, xv);

                    float A0 = bs0, A1 = bs1, A2 = bs2, A3 = bs3;
                    float B0 = 0.f, B1 = 0.f, B2 = 0.f, B3 = 0.f;
                    // hoist broadcasts in 16-groups (amortize SGPR hazards)
                    h2_t sv[16], sw[16];
#pragma unroll
                    for (int kk = 0; kk < 16; ++kk) sv[kk] = bc(x2r, kk);
#pragma unroll
                    for (int kk = 0; kk < 16; ++kk) {
                        A0 = dot2acc(w[0][kk], sv[kk], A0);
                        A1 = dot2acc(w[1][kk], sv[kk], A1);
                        A2 = dot2acc(w[2][kk], sv[kk], A2);
                        A3 = dot2acc(w[3][kk], sv[kk], A3);
                    }
#pragma unroll
                    for (int kk = 0; kk < 16; ++kk) sw[kk] = bc(x2r, kk + 16);
#pragma unroll
                    for (int kk = 0; kk < 16; ++kk) {
                        B0 = dot2acc(w[0][kk + 16], sw[kk], B0);
                        B1 = dot2acc(w[1][kk + 16], sw[kk], B1);
                        B2 = dot2acc(w[2][kk + 16], sw[kk], B2);
                        B3 = dot2acc(w[3][kk + 16], sw[kk], B3);
                    }
                    float4 r;
                    r.x = A0 + B0; r.y = A1 + B1; r.z = A2 + B2; r.w = A3 + B3;
                    xg[k & 1][s][lane] = r;
                }
            }
        } else if (c >= 0) {
            // preload the whole chunk's xg rows into registers
            float4 xr[CHUNK];
#pragma unroll
            for (int s = 0; s < CHUNK; ++s) xr[s] = xg[c & 1][s][lane];

#pragma unroll
            for (int s = 0; s < CHUNK; ++s) {
                float A0 = 0.f, A1 = 0.f, A2 = 0.f, A3 = 0.f;
                float B0 = 0.f, B1 = 0.f, B2 = 0.f, B3 = 0.f;
                h2_t sv[16], sw[16];
#pragma unroll
                for (int kk = 0; kk < 16; ++kk) sv[kk] = bc(h2r, kk);
#pragma unroll
                for (int kk = 0; kk < 16; ++kk) {
                    A0 = dot2acc(w[0][kk], sv[kk], A0);
                    A1 = dot2acc(w[1][kk], sv[kk], A1);
                    A2 = dot2acc(w[2][kk], sv[kk], A2);
                    A3 = dot2acc(w[3][kk], sv[kk], A3);
                }
#pragma unroll
                for (int kk = 0; kk < 16; ++kk) sw[kk] = bc(h2r, kk + 16);
#pragma unroll
                for (int kk = 0; kk < 16; ++kk) {
                    B0 = dot2acc(w[0][kk + 16], sw[kk], B0);
                    B1 = dot2acc(w[1][kk + 16], sw[kk], B1);
                    B2 = dot2acc(w[2][kk + 16], sw[kk], B2);
                    B3 = dot2acc(w[3][kk + 16], sw[kk], B3);
                }
                float pi = A0 + B0 + xr[s].x;
                float pf = A1 + B1 + xr[s].y;
                float pg = A2 + B2 + xr[s].z;
                float po = A3 + B3 + xr[s].w;

                float gi = sigm(pi);
                float gf = sigm(pf);
                float gg = tanh_fast(pg);
                float go = sigm(po);
                c_state = gf * c_state + gi * gg;
                float h = go * tanh_fast(c_state);

                ob[(c * CHUNK + s) * HID] = h;

                // repack h -> (h[2k],h[2k+1]) f16 pair in lane k via bpermute
                _Float16 hf = (_Float16)h;
                int hv = (int)__builtin_bit_cast(unsigned short, hf);  // zero-ext
                int p0 = __builtin_amdgcn_ds_bpermute(a0i, hv);
                int p1 = __builtin_amdgcn_ds_bpermute(a0i + 4, hv);
                h2r = p0 | (p1 << 16);
            }
        }
        __syncthreads();
    }
}

// Fallback scratch in case ws_size is too small (33.6 MB needed)
__device__ float g_scratch[512 * 256 * 64];

extern "C" void kernel_launch(void* const* d_in, const int* in_sizes, int n_in,
                              void* d_out, int out_size, void* d_ws, size_t ws_size,
                              hipStream_t stream) {
    const float* x = (const float*)d_in[0];
    float* out = (float*)d_out;

    const size_t buf_elems = (size_t)512 * 256 * 64;
    float* buf;
    if (ws_size >= buf_elems * sizeof(float)) {
        buf = (float*)d_ws;
    } else {
        void* p = nullptr;
        hipGetSymbolAddress(&p, HIP_SYMBOL(g_scratch));
        buf = (float*)p;
    }

    auto launch = [&](const float* xi, float* ho, int wb) {
        lstm_layer_pc<<<512, 128, 0, stream>>>(
            xi, ho,
            (const float*)d_in[wb + 0],   // Wih
            (const float*)d_in[wb + 1],   // Whh
            (const float*)d_in[wb + 2],   // bih
            (const float*)d_in[wb + 3]);  // bhh
    };

    launch(x,   buf, 1);    // enc0
    launch(buf, out, 5);    // enc1
    launch(out, buf, 9);    // dec0
    launch(buf, out, 13);   // dec1 (final)
}

// Round 5
// 533.158 us; speedup vs baseline: 4.0747x; 1.1088x over previous
//
#include <hip/hip_runtime.h>

// LSTM autoencoder: 4 layers 64->64, B=512, T=256.
// Producer/consumer wave pair per batch element (block=128):
//   wave0 (producer): xg[t,g] = W_ih . x_t + b, one CHUNK ahead, dbuf in LDS.
//   wave1 (consumer): recurrence  g = xg + W_hh . h ; activations; c,h update.
// Round-5 delta: broadcast operands via wave-uniform ds_read_b128 (VGPR dest,
// no VALU->SGPR->VALU hazards) instead of v_readlane. h goes through a 128 B
// LDS buffer (ds_write_b16 in epilogue); producer stages converted x-pairs in
// an LDS scratch at chunk start. Weights stay f16x2 in VGPRs; f32 accumulate.

typedef _Float16 h2_t __attribute__((ext_vector_type(2)));

#define T_SEQ  256
#define HID    64
#define CHUNK  8
#define NCHUNK (T_SEQ / CHUNK)   // 32

__device__ __forceinline__ float fast_rcp(float x) { return __builtin_amdgcn_rcpf(x); }
__device__ __forceinline__ float sigm(float x) { return fast_rcp(1.0f + __expf(-x)); }
__device__ __forceinline__ float tanh_fast(float x) {
    return 2.0f * fast_rcp(1.0f + __expf(-2.0f * x)) - 1.0f;
}
__device__ __forceinline__ float dot2acc(h2_t a, h2_t b, float c) {
    return __builtin_amdgcn_fdot2(a, b, c, false);
}
__device__ __forceinline__ h2_t asb(int v) { return __builtin_bit_cast(h2_t, v); }

__global__ __launch_bounds__(128, 1)
void lstm_layer_pc2(const float* __restrict__ x,    // [B, T, 64]
                    float* __restrict__ out,        // [B, T, 64]
                    const float* __restrict__ Wih,  // [256, 64]
                    const float* __restrict__ Whh,  // [256, 64]
                    const float* __restrict__ bih,  // [256]
                    const float* __restrict__ bhh)  // [256]
{
    __shared__ float4   xg[2][CHUNK][HID];   // 16 KB double-buffered xg chunks
    __shared__ int      xs[CHUNK][32];       // 1 KB producer-only x-pair stage
    __shared__ _Float16 hbuf[HID];           // 128 B consumer h state (f16)

    const int  tid  = threadIdx.x;
    const int  lane = tid & 63;
    const bool isC  = (tid >= 64);           // wave1 = consumer
    const int  b    = blockIdx.x;

    // ---- role weight matrix (rows g*64+lane), packed f16x2 in VGPRs ----
    h2_t w[4][32];
    {
        const float* Wm = isC ? Whh : Wih;
#pragma unroll
        for (int g = 0; g < 4; ++g) {
            const float2* wr = (const float2*)(Wm + (g * 64 + lane) * HID);
#pragma unroll
            for (int k = 0; k < 32; ++k) {
                float2 v = wr[k];
                h2_t p; p.x = (_Float16)v.x; p.y = (_Float16)v.y;
                w[g][k] = p;
            }
        }
    }

    // ---- producer-only state: biases + x prefetch registers ----
    float bs0 = 0.f, bs1 = 0.f, bs2 = 0.f, bs3 = 0.f;
    const float2* xp = (const float2*)(x + (size_t)b * T_SEQ * HID) + (lane & 31);
    float2 nx[CHUNK];
    if (!isC) {
        bs0 = bih[lane]       + bhh[lane];
        bs1 = bih[64 + lane]  + bhh[64 + lane];
        bs2 = bih[128 + lane] + bhh[128 + lane];
        bs3 = bih[192 + lane] + bhh[192 + lane];
#pragma unroll
        for (int s = 0; s < CHUNK; ++s) nx[s] = xp[s * 32];   // chunk 0
    } else {
        if (lane < 16) ((int2*)hbuf)[lane] = make_int2(0, 0); // h0 = 0
    }

    float c_state = 0.0f;
    float* ob = out + (size_t)b * T_SEQ * HID + lane;

    // iteration c: producer fills chunk c+1, consumer drains chunk c
    for (int c = -1; c < NCHUNK; ++c) {
        if (!isC) {
            const int k = c + 1;
            if (k < NCHUNK) {
                // stage this chunk's x pairs (f16) into LDS scratch
                if (lane < 32) {
#pragma unroll
                    for (int s = 0; s < CHUNK; ++s) {
                        h2_t xv; xv.x = (_Float16)nx[s].x; xv.y = (_Float16)nx[s].y;
                        xs[s][lane] = __builtin_bit_cast(int, xv);
                    }
                }
                if (k + 1 < NCHUNK) {        // issue next chunk's loads EARLY
#pragma unroll
                    for (int s = 0; s < CHUNK; ++s)
                        nx[s] = xp[((k + 1) * CHUNK + s) * 32];
                }
#pragma unroll
                for (int s = 0; s < CHUNK; ++s) {
                    // wave-uniform broadcast reads: 8 x b128 = 32 pairs
                    int4 hv[8];
#pragma unroll
                    for (int j = 0; j < 8; ++j) hv[j] = ((const int4*)xs[s])[j];

                    float A0 = bs0, A1 = bs1, A2 = bs2, A3 = bs3;
                    float B0 = 0.f, B1 = 0.f, B2 = 0.f, B3 = 0.f;
#pragma unroll
                    for (int j = 0; j < 4; ++j) {
                        const int kk = j * 4;
                        A0 = dot2acc(w[0][kk    ], asb(hv[j].x), A0);
                        A1 = dot2acc(w[1][kk    ], asb(hv[j].x), A1);
                        A2 = dot2acc(w[2][kk    ], asb(hv[j].x), A2);
                        A3 = dot2acc(w[3][kk    ], asb(hv[j].x), A3);
                        A0 = dot2acc(w[0][kk + 1], asb(hv[j].y), A0);
                        A1 = dot2acc(w[1][kk + 1], asb(hv[j].y), A1);
                        A2 = dot2acc(w[2][kk + 1], asb(hv[j].y), A2);
                        A3 = dot2acc(w[3][kk + 1], asb(hv[j].y), A3);
                        A0 = dot2acc(w[0][kk + 2], asb(hv[j].z), A0);
                        A1 = dot2acc(w[1][kk + 2], asb(hv[j].z), A1);
                        A2 = dot2acc(w[2][kk + 2], asb(hv[j].z), A2);
                        A3 = dot2acc(w[3][kk + 2], asb(hv[j].z), A3);
                        A0 = dot2acc(w[0][kk + 3], asb(hv[j].w), A0);
                        A1 = dot2acc(w[1][kk + 3], asb(hv[j].w), A1);
                        A2 = dot2acc(w[2][kk + 3], asb(hv[j].w), A2);
                        A3 = dot2acc(w[3][kk + 3], asb(hv[j].w), A3);
                    }
#pragma unroll
                    for (int j = 4; j < 8; ++j) {
                        const int kk = j * 4;
                        B0 = dot2acc(w[0][kk    ], asb(hv[j].x), B0);
                        B1 = dot2acc(w[1][kk    ], asb(hv[j].x), B1);
                        B2 = dot2acc(w[2][kk    ], asb(hv[j].x), B2);
                        B3 = dot2acc(w[3][kk    ], asb(hv[j].x), B3);
                        B0 = dot2acc(w[0][kk + 1], asb(hv[j].y), B0);
                        B1 = dot2acc(w[1][kk + 1], asb(hv[j].y), B1);
                        B2 = dot2acc(w[2][kk + 1], asb(hv[j].y), B2);
                        B3 = dot2acc(w[3][kk + 1], asb(hv[j].y), B3);
                        B0 = dot2acc(w[0][kk + 2], asb(hv[j].z), B0);
                        B1 = dot2acc(w[1][kk + 2], asb(hv[j].z), B1);
                        B2 = dot2acc(w[2][kk + 2], asb(hv[j].z), B2);
                        B3 = dot2acc(w[3][kk + 2], asb(hv[j].z), B3);
                        B0 = dot2acc(w[0][kk + 3], asb(hv[j].w), B0);
                        B1 = dot2acc(w[1][kk + 3], asb(hv[j].w), B1);
                        B2 = dot2acc(w[2][kk + 3], asb(hv[j].w), B2);
                        B3 = dot2acc(w[3][kk + 3], asb(hv[j].w), B3);
                    }
                    float4 r;
                    r.x = A0 + B0; r.y = A1 + B1; r.z = A2 + B2; r.w = A3 + B3;
                    xg[k & 1][s][lane] = r;
                }
            }
        } else if (c >= 0) {
            // preload the whole chunk's xg rows into registers
            float4 xr[CHUNK];
#pragma unroll
            for (int s = 0; s < CHUNK; ++s) xr[s] = xg[c & 1][s][lane];

#pragma unroll
            for (int s = 0; s < CHUNK; ++s) {
                // wave-uniform broadcast of h: 8 x b128 = 32 pairs
                int4 hv[8];
#pragma unroll
                for (int j = 0; j < 8; ++j) hv[j] = ((const int4*)hbuf)[j];

                float A0 = xr[s].x, A1 = xr[s].y, A2 = xr[s].z, A3 = xr[s].w;
                float B0 = 0.f, B1 = 0.f, B2 = 0.f, B3 = 0.f;
#pragma unroll
                for (int j = 0; j < 4; ++j) {
                    const int kk = j * 4;
                    A0 = dot2acc(w[0][kk    ], asb(hv[j].x), A0);
                    A1 = dot2acc(w[1][kk    ], asb(hv[j].x), A1);
                    A2 = dot2acc(w[2][kk    ], asb(hv[j].x), A2);
                    A3 = dot2acc(w[3][kk    ], asb(hv[j].x), A3);
                    A0 = dot2acc(w[0][kk + 1], asb(hv[j].y), A0);
                    A1 = dot2acc(w[1][kk + 1], asb(hv[j].y), A1);
                    A2 = dot2acc(w[2][kk + 1], asb(hv[j].y), A2);
                    A3 = dot2acc(w[3][kk + 1], asb(hv[j].y), A3);
                    A0 = dot2acc(w[0][kk + 2], asb(hv[j].z), A0);
                    A1 = dot2acc(w[1][kk + 2], asb(hv[j].z), A1);
                    A2 = dot2acc(w[2][kk + 2], asb(hv[j].z), A2);
                    A3 = dot2acc(w[3][kk + 2], asb(hv[j].z), A3);
                    A0 = dot2acc(w[0][kk + 3], asb(hv[j].w), A0);
                    A1 = dot2acc(w[1][kk + 3], asb(hv[j].w), A1);
                    A2 = dot2acc(w[2][kk + 3], asb(hv[j].w), A2);
                    A3 = dot2acc(w[3][kk + 3], asb(hv[j].w), A3);
                }
#pragma unroll
                for (int j = 4; j < 8; ++j) {
                    const int kk = j * 4;
                    B0 = dot2acc(w[0][kk    ], asb(hv[j].x), B0);
                    B1 = dot2acc(w[1][kk    ], asb(hv[j].x), B1);
                    B2 = dot2acc(w[2][kk    ], asb(hv[j].x), B2);
                    B3 = dot2acc(w[3][kk    ], asb(hv[j].x), B3);
                    B0 = dot2acc(w[0][kk + 1], asb(hv[j].y), B0);
                    B1 = dot2acc(w[1][kk + 1], asb(hv[j].y), B1);
                    B2 = dot2acc(w[2][kk + 1], asb(hv[j].y), B2);
                    B3 = dot2acc(w[3][kk + 1], asb(hv[j].y), B3);
                    B0 = dot2acc(w[0][kk + 2], asb(hv[j].z), B0);
                    B1 = dot2acc(w[1][kk + 2], asb(hv[j].z), B1);
                    B2 = dot2acc(w[2][kk + 2], asb(hv[j].z), B2);
                    B3 = dot2acc(w[3][kk + 2], asb(hv[j].z), B3);
                    B0 = dot2acc(w[0][kk + 3], asb(hv[j].w), B0);
                    B1 = dot2acc(w[1][kk + 3], asb(hv[j].w), B1);
                    B2 = dot2acc(w[2][kk + 3], asb(hv[j].w), B2);
                    B3 = dot2acc(w[3][kk + 3], asb(hv[j].w), B3);
                }
                float pi = A0 + B0;
                float pf = A1 + B1;
                float pg = A2 + B2;
                float po = A3 + B3;

                float gi = sigm(pi);
                float gf = sigm(pf);
                float gg = tanh_fast(pg);
                float go = sigm(po);
                c_state = gf * c_state + gi * gg;
                float h = go * tanh_fast(c_state);

                ob[(c * CHUNK + s) * HID] = h;
                hbuf[lane] = (_Float16)h;     // next step's broadcast source
            }
        }
        __syncthreads();
    }
}

// Fallback scratch in case ws_size is too small (33.6 MB needed)
__device__ float g_scratch[512 * 256 * 64];

extern "C" void kernel_launch(void* const* d_in, const int* in_sizes, int n_in,
                              void* d_out, int out_size, void* d_ws, size_t ws_size,
                              hipStream_t stream) {
    const float* x = (const float*)d_in[0];
    float* out = (float*)d_out;

    const size_t buf_elems = (size_t)512 * 256 * 64;
    float* buf;
    if (ws_size >= buf_elems * sizeof(float)) {
        buf = (float*)d_ws;
    } else {
        void* p = nullptr;
        hipGetSymbolAddress(&p, HIP_SYMBOL(g_scratch));
        buf = (float*)p;
    }

    auto launch = [&](const float* xi, float* ho, int wb) {
        lstm_layer_pc2<<<512, 128, 0, stream>>>(
            xi, ho,
            (const float*)d_in[wb + 0],   // Wih
            (const float*)d_in[wb + 1],   // Whh
            (const float*)d_in[wb + 2],   // bih
            (const float*)d_in[wb + 3]);  // bhh
    };

    launch(x,   buf, 1);    // enc0
    launch(buf, out, 5);    // enc1
    launch(out, buf, 9);    // dec0
    launch(buf, out, 13);   // dec1 (final)
}

// Round 6
// 439.393 us; speedup vs baseline: 4.9443x; 1.2134x over previous
//
#include <hip/hip_runtime.h>

// LSTM autoencoder: 4 layers 64->64, B=512, T=256 — fused single-launch,
// MFMA recurrence with cross-layer software pipeline.
//
// Grid: 256 blocks x 512 threads. Block owns 2 batch elements AND all 4
// layers. Wave w = (layer L = w>>1, M-half mh = w&1). At tick tau, layer L
// computes its step t = tau - L (wavefront schedule, 259 ticks total).
//
// Per tick, per layer: G[256 gates, 2 el] = [Wih|Whh] . [v; h] via
// mfma_f32_16x16x32_f16 (8 M-tiles/wave x 4 K-chunks = 32 MFMA, A-frags of
// the weights persist in VGPRs, statically indexed — round-3's scratch-spill
// bug was dynamic indexing). v = prev layer's h (LDS, f16, parity tau&1)
// or global x for layer 0. Bias is folded into the MFMA C-init fragments.
// Epilogue: thread (wave=(L,el), lane=hid) owns one unit's c_state in a
// register across all ticks; gates arrive via one LDS round trip (G).
// MFMA fragment layouts are the round-3-verified ones:
//   A[m=lane&15][k=quad*8+j], B[k=quad*8+j][n=lane&15], C col=lane&15,
//   row = tile*16 + quad*4 + reg.

typedef _Float16 f16x8 __attribute__((ext_vector_type(8)));
typedef float    f32x4 __attribute__((ext_vector_type(4)));

#define TSEQ 256
#define GSTR 264   // f32 stride per (L, el) gate row in LDS (256 + pad)

__device__ __forceinline__ float fast_rcp(float x) { return __builtin_amdgcn_rcpf(x); }
__device__ __forceinline__ float sigm(float x) { return fast_rcp(1.0f + __expf(-x)); }
__device__ __forceinline__ float tanh_fast(float x) {
    return 2.0f * fast_rcp(1.0f + __expf(-2.0f * x)) - 1.0f;
}

__device__ __forceinline__ f16x8 mkfrag(float4 a, float4 b) {
    f16x8 f;
    f[0] = (_Float16)a.x; f[1] = (_Float16)a.y; f[2] = (_Float16)a.z; f[3] = (_Float16)a.w;
    f[4] = (_Float16)b.x; f[5] = (_Float16)b.y; f[6] = (_Float16)b.z; f[7] = (_Float16)b.w;
    return f;
}

__global__ __launch_bounds__(512, 2)
void lstm_fused(const float* __restrict__ x,     // [512, 256, 64]
                float* __restrict__ out,         // [512, 256, 64]
                const float* __restrict__ Wih0, const float* __restrict__ Whh0,
                const float* __restrict__ bi0,  const float* __restrict__ bh0,
                const float* __restrict__ Wih1, const float* __restrict__ Whh1,
                const float* __restrict__ bi1,  const float* __restrict__ bh1,
                const float* __restrict__ Wih2, const float* __restrict__ Whh2,
                const float* __restrict__ bi2,  const float* __restrict__ bh2,
                const float* __restrict__ Wih3, const float* __restrict__ Whh3,
                const float* __restrict__ bi3,  const float* __restrict__ bh3)
{
    __shared__ float    G[4 * 2 * GSTR];          // gates [L][el][256+pad] f32
    __shared__ _Float16 Hb[4 * 2 * 2 * 64];       // h [L][parity][el][64] f16

    const int tid  = threadIdx.x;
    const int wave = tid >> 6;
    const int lane = tid & 63;
    const int L    = wave >> 1;       // layer 0..3
    const int mh   = wave & 1;        // M-half (gates [mh*128, mh*128+128))
    const int q    = lane >> 4;       // quad
    const int n    = lane & 15;       // MFMA row/col index
    const int elB  = n & 1;           // B-frag element (cols 0,1 valid)
    const int b0   = blockIdx.x * 2;

    const float* Wih = (L == 0) ? Wih0 : (L == 1) ? Wih1 : (L == 2) ? Wih2 : Wih3;
    const float* Whh = (L == 0) ? Whh0 : (L == 1) ? Whh1 : (L == 2) ? Whh2 : Whh3;
    const float* bi  = (L == 0) ? bi0  : (L == 1) ? bi1  : (L == 2) ? bi2  : bi3;
    const float* bh  = (L == 0) ? bh0  : (L == 1) ? bh1  : (L == 2) ? bh2  : bh3;

    // ---- persistent A-fragments (8 tiles x 4 K-chunks) + bias C-frags ----
    f16x8 A[8][4];
    f32x4 Cb[8];
#pragma unroll
    for (int ti = 0; ti < 8; ++ti) {
        const int row = mh * 128 + ti * 16 + n;
#pragma unroll
        for (int c = 0; c < 4; ++c) {
            const float* src = (c < 2 ? Wih + row * 64 + c * 32
                                      : Whh + row * 64 + (c - 2) * 32) + q * 8;
            f16x8 f;
#pragma unroll
            for (int j = 0; j < 8; ++j) f[j] = (_Float16)src[j];
            A[ti][c] = f;
        }
        f32x4 cb;
#pragma unroll
        for (int r = 0; r < 4; ++r) {
            const int br = mh * 128 + ti * 16 + q * 4 + r;
            cb[r] = bi[br] + bh[br];
        }
        Cb[ti] = cb;
    }

    // ---- zero h state (both parities) ----
    ((int*)Hb)[tid] = 0;   // 2048 B = 512 ints
    float cst = 0.0f;
    float* outp = out + ((size_t)(b0 + mh) * TSEQ) * 64 + lane;  // L==3 only

    __syncthreads();

    for (int tau = 0; tau < TSEQ + 3; ++tau) {
        const int  t   = tau - L;
        const bool act = (t >= 0) && (t < TSEQ);   // wave-uniform
        const int  pr  = (tau + 1) & 1;            // read parity
        const int  pw  = tau & 1;                  // write parity

        if (act) {
            // ---- B-fragments: own h (K 64..127) and input v (K 0..63) ----
            const _Float16* hp = Hb + ((L * 2 + pr) * 2 + elB) * 64;
            f16x8 hf0 = *(const f16x8*)(hp + q * 8);
            f16x8 hf1 = *(const f16x8*)(hp + 32 + q * 8);
            f16x8 vf0, vf1;
            if (L == 0) {
                const float* xp = x + ((size_t)(b0 + elB) * TSEQ + t) * 64 + q * 8;
                float4 a  = *(const float4*)(xp);
                float4 b  = *(const float4*)(xp + 4);
                float4 c2 = *(const float4*)(xp + 32);
                float4 d  = *(const float4*)(xp + 36);
                vf0 = mkfrag(a, b);
                vf1 = mkfrag(c2, d);
            } else {
                const _Float16* vp = Hb + (((L - 1) * 2 + pr) * 2 + elB) * 64;
                vf0 = *(const f16x8*)(vp + q * 8);
                vf1 = *(const f16x8*)(vp + 32 + q * 8);
            }

            // ---- 32 MFMA: h-chunks first (hides L0's global-x latency) ----
#pragma unroll
            for (int ti = 0; ti < 8; ++ti) {
                f32x4 C = Cb[ti];
                C = __builtin_amdgcn_mfma_f32_16x16x32_f16(A[ti][2], hf0, C, 0, 0, 0);
                C = __builtin_amdgcn_mfma_f32_16x16x32_f16(A[ti][3], hf1, C, 0, 0, 0);
                C = __builtin_amdgcn_mfma_f32_16x16x32_f16(A[ti][0], vf0, C, 0, 0, 0);
                C = __builtin_amdgcn_mfma_f32_16x16x32_f16(A[ti][1], vf1, C, 0, 0, 0);
                if (n < 2) {
                    float4 st; st.x = C[0]; st.y = C[1]; st.z = C[2]; st.w = C[3];
                    *(float4*)&G[(L * 2 + n) * GSTR + mh * 128 + ti * 16 + q * 4] = st;
                }
            }
        }
        __syncthreads();

        if (act) {
            // ---- epilogue: this thread owns unit (L, el=mh, hid=lane) ----
            const float* gc = &G[(L * 2 + mh) * GSTR];
            float pi = gc[lane];
            float pf = gc[64 + lane];
            float pg = gc[128 + lane];
            float po = gc[192 + lane];

            float gi = sigm(pi);
            float gf = sigm(pf);
            float gg = tanh_fast(pg);
            float go = sigm(po);
            cst = gf * cst + gi * gg;
            float h = go * tanh_fast(cst);

            if (L == 3) outp[t * 64] = h;                       // final output
            Hb[((L * 2 + pw) * 2 + mh) * 64 + lane] = (_Float16)h;
        }
        __syncthreads();
    }
}

extern "C" void kernel_launch(void* const* d_in, const int* in_sizes, int n_in,
                              void* d_out, int out_size, void* d_ws, size_t ws_size,
                              hipStream_t stream) {
    const float* x = (const float*)d_in[0];
    float* out = (float*)d_out;

    lstm_fused<<<256, 512, 0, stream>>>(
        x, out,
        (const float*)d_in[1],  (const float*)d_in[2],
        (const float*)d_in[3],  (const float*)d_in[4],
        (const float*)d_in[5],  (const float*)d_in[6],
        (const float*)d_in[7],  (const float*)d_in[8],
        (const float*)d_in[9],  (const float*)d_in[10],
        (const float*)d_in[11], (const float*)d_in[12],
        (const float*)d_in[13], (const float*)d_in[14],
        (const float*)d_in[15], (const float*)d_in[16]);
}